// Round 5
// baseline (339.471 us; speedup 1.0000x reference)
//
#include <hip/hip_runtime.h>

// AUGRU, round 5: two-pass, transposed (weights-as-A) recurrence.
//  All MFMAs compute D[hidden][batch] = W-frag(A) x h^T-frag(B).
//  Thread owns (hidden lk*4+q, batch l15): h/rh exchange = 1 ds_write_b64,
//  z'/h(f32)/r*h stay in registers, attention = 1 b32 read/step.
// Pass 1 (xproj) produces preacts in [t][bblk][gate][batch16][hidden128] bf16.
// Fallback: proven single-kernel (R2) if ws too small.

#define T_N   200
#define I_DIM 128
#define H_DIM 128
#define NBLK  64

typedef float  f32x4  __attribute__((ext_vector_type(4)));
typedef __bf16 bf16x4 __attribute__((ext_vector_type(4)));
typedef __bf16 bf16x8 __attribute__((ext_vector_type(8)));

// rec LDS: hT / rhT as [batch 16][hidden 128 + 8 pad] bf16
#define LDH_STRIDE 136
// attention: [t][batch 16] f32
// preact: per (t,bblk): 3 gates * 16 batch * 128 hidden * 2B = 12288 B
#define GATE_BYTES 4096
#define PB_BYTES   (3 * GATE_BYTES)
#define PRE_BYTES  ((size_t)T_N * NBLK * PB_BYTES)   // 157,286,400

// fallback LDS
#define LDA_STRIDE 264
#define LATT_STRIDE 201

__device__ __forceinline__ float fast_sigmoid(float x) {
  float e = __builtin_amdgcn_exp2f(-1.4426950408889634f * x);
  return __builtin_amdgcn_rcpf(1.0f + e);
}
__device__ __forceinline__ float fast_tanh(float x) {
  float e = __builtin_amdgcn_exp2f(2.8853900817779268f * x);
  return 1.0f - 2.0f * __builtin_amdgcn_rcpf(1.0f + e);
}
__device__ __forceinline__ void barrier_lds() {
  asm volatile("s_waitcnt lgkmcnt(0)\n\ts_barrier" ::: "memory");
}
__device__ __forceinline__ bf16x8 pack8(float4 a, float4 b) {
  bf16x8 t;
  t[0] = (__bf16)a.x; t[1] = (__bf16)a.y; t[2] = (__bf16)a.z; t[3] = (__bf16)a.w;
  t[4] = (__bf16)b.x; t[5] = (__bf16)b.y; t[6] = (__bf16)b.z; t[7] = (__bf16)b.w;
  return t;
}

// ---------------------------------------------------------------------------
// Pass 1: x-projections (transposed). grid = 64 bblk * 20 tchunks, 256 thr.
// ---------------------------------------------------------------------------
#define TCHUNK 10
__global__ __launch_bounds__(256, 2)
void xproj_kernel(const float* __restrict__ inputs,
                  const float* __restrict__ Wz, const float* __restrict__ bz,
                  const float* __restrict__ Wr, const float* __restrict__ br,
                  const float* __restrict__ Wh, const float* __restrict__ bh,
                  char* __restrict__ pre) {
  const int tid  = threadIdx.x;
  const int w    = tid >> 6;
  const int l    = tid & 63;
  const int l15  = l & 15;
  const int lk   = l >> 4;
  const int bblk = blockIdx.x & (NBLK - 1);
  const int t0   = (blockIdx.x >> 6) * TCHUNK;
  const int r0   = bblk * 16;

  // A-frags: W x-part (k=0..127). slot s: gate g=s>>1, hid0 = w*32+(s&1)*16.
  // lane: W[hid0+l15][kt*32+lk*8+e]
  bf16x8 wb[24];
  f32x4  bias4[6];
  #pragma unroll
  for (int s = 0; s < 6; ++s) {
    int hid0 = w * 32 + (s & 1) * 16;
    const float* Wp; const float* bp;
    if (s < 2)      { Wp = Wz; bp = bz; }
    else if (s < 4) { Wp = Wr; bp = br; }
    else            { Wp = Wh; bp = bh; }
    float4 bv = *(const float4*)&bp[hid0 + lk * 4];
    bias4[s][0] = bv.x; bias4[s][1] = bv.y; bias4[s][2] = bv.z; bias4[s][3] = bv.w;
    const float* Wrow = Wp + (size_t)(hid0 + l15) * 256;
    #pragma unroll
    for (int kt = 0; kt < 4; ++kt) {
      const float* p = Wrow + kt * 32 + lk * 8;
      wb[s * 4 + kt] = pack8(*(const float4*)p, *(const float4*)(p + 4));
    }
  }

  const float* xbase = inputs + (size_t)(r0 + l15) * (T_N * I_DIM);

  #pragma unroll 2
  for (int ti = 0; ti < TCHUNK; ++ti) {
    const int t = t0 + ti;
    // B-frags: x^T. lane: x[batch l15][kt*32+lk*8+e]
    bf16x8 xf[4];
    #pragma unroll
    for (int kt = 0; kt < 4; ++kt) {
      const float* p = xbase + (size_t)t * I_DIM + kt * 32 + lk * 8;
      xf[kt] = pack8(*(const float4*)p, *(const float4*)(p + 4));
    }
    f32x4 acc[6];
    #pragma unroll
    for (int s = 0; s < 6; ++s) acc[s] = bias4[s];
    #pragma unroll
    for (int kt = 0; kt < 4; ++kt)
      #pragma unroll
      for (int s = 0; s < 6; ++s)
        acc[s] = __builtin_amdgcn_mfma_f32_16x16x32_bf16(wb[s * 4 + kt], xf[kt], acc[s], 0, 0, 0);

    // D[hidden hid0+lk*4+q][batch l15] -> store [gate][batch][hidden] b64
    char* base = pre + ((size_t)t * NBLK + bblk) * PB_BYTES + (size_t)l15 * 256;
    #pragma unroll
    for (int s = 0; s < 6; ++s) {
      int g    = s >> 1;
      int hid0 = w * 32 + (s & 1) * 16;
      bf16x4 v;
      v[0] = (__bf16)acc[s][0]; v[1] = (__bf16)acc[s][1];
      v[2] = (__bf16)acc[s][2]; v[3] = (__bf16)acc[s][3];
      *(bf16x4*)(base + g * GATE_BYTES + (hid0 + lk * 4) * 2) = v;
    }
  }
}

// ---------------------------------------------------------------------------
// Pass 2: recurrence (transposed). grid = 64 blocks, 512 threads (8 waves).
// ---------------------------------------------------------------------------
__global__ __launch_bounds__(512, 2)
void augru_rec_kernel(const char* __restrict__ pre,
                      const float* __restrict__ attn,
                      const float* __restrict__ Wz,
                      const float* __restrict__ Wr,
                      const float* __restrict__ Wh,
                      float* __restrict__ out) {
  __shared__ __align__(16) short lds_h [16 * LDH_STRIDE];  // hT  [batch][hidden]
  __shared__ __align__(16) short lds_rh[16 * LDH_STRIDE];  // rhT [batch][hidden]
  __shared__ float lds_att[T_N * 16];                      // [t][batch]

  const int tid   = threadIdx.x;
  const int w     = tid >> 6;        // 0..7 : wave's hidden block
  const int l     = tid & 63;
  const int l15   = l & 15;          // batch lane
  const int lk    = l >> 4;
  const int r0    = blockIdx.x * 16;
  const int myhid = w * 16 + lk * 4; // thread's 4 hidden rows (contiguous)

  // ---- prologue ----
  for (int idx = tid; idx < T_N * 16; idx += 512) {
    int t = idx >> 4, b = idx & 15;
    lds_att[idx] = attn[(size_t)(r0 + b) * T_N + t];
  }
  for (int idx = tid; idx < 16 * LDH_STRIDE; idx += 512) lds_h[idx] = 0;

  // ---- A-frags: recurrent weights (k = 128..255), rows = hidden w*16+l15 ----
  bf16x8 wzA[4], wrA[4], whA[4];
  {
    const float* pz = Wz + (size_t)(w * 16 + l15) * 256 + 128;
    const float* pr = Wr + (size_t)(w * 16 + l15) * 256 + 128;
    const float* ph = Wh + (size_t)(w * 16 + l15) * 256 + 128;
    #pragma unroll
    for (int kt = 0; kt < 4; ++kt) {
      const float* a = pz + kt * 32 + lk * 8;
      wzA[kt] = pack8(*(const float4*)a, *(const float4*)(a + 4));
      const float* b = pr + kt * 32 + lk * 8;
      wrA[kt] = pack8(*(const float4*)b, *(const float4*)(b + 4));
      const float* c = ph + kt * 32 + lk * 8;
      whA[kt] = pack8(*(const float4*)c, *(const float4*)(c + 4));
    }
  }

  float hreg[4];
  #pragma unroll
  for (int q = 0; q < 4; ++q) hreg[q] = 0.0f;

  // ---- preact ring (depth 2): [t][bblk][gate][batch][hidden] ----
  const char* pb = pre + (size_t)blockIdx.x * PB_BYTES + (size_t)l15 * 256 + myhid * 2;
  const size_t tstride = (size_t)NBLK * PB_BYTES;
  bf16x4 pf[2][3];
  #pragma unroll
  for (int d = 0; d < 2; ++d)
    #pragma unroll
    for (int g = 0; g < 3; ++g)
      pf[d][g] = *(const bf16x4*)(pb + d * tstride + g * GATE_BYTES);

  __syncthreads();

  #pragma unroll 2
  for (int t = 0; t < T_N; ++t) {
    // consume preact t
    float pzv[4], prv[4], phv[4];
    #pragma unroll
    for (int q = 0; q < 4; ++q) {
      pzv[q] = (float)pf[t & 1][0][q];
      prv[q] = (float)pf[t & 1][1][q];
      phv[q] = (float)pf[t & 1][2][q];
    }
    // prefetch t+2
    if (t + 2 < T_N) {
      const char* b = pb + (size_t)(t + 2) * tstride;
      #pragma unroll
      for (int g = 0; g < 3; ++g)
        pf[t & 1][g] = *(const bf16x4*)(b + g * GATE_BYTES);
    }

    // B-frag: h^T. lane: h[batch l15][kt*32+lk*8+e]
    bf16x8 hb[4];
    #pragma unroll
    for (int kt = 0; kt < 4; ++kt)
      hb[kt] = *(const bf16x8*)&lds_h[l15 * LDH_STRIDE + kt * 32 + lk * 8];
    const float av = lds_att[t * 16 + l15];

    // phase 1: zT,rT = preact + W_h x h^T (split-k depth 2)
    f32x4 zA, zB, rA, rB;
    { f32x4 a; a[0]=pzv[0]; a[1]=pzv[1]; a[2]=pzv[2]; a[3]=pzv[3]; zA = a; }
    { f32x4 a; a[0]=prv[0]; a[1]=prv[1]; a[2]=prv[2]; a[3]=prv[3]; rA = a; }
    { f32x4 z; z[0]=0.f; z[1]=0.f; z[2]=0.f; z[3]=0.f; zB = z; rB = z; }
    zA = __builtin_amdgcn_mfma_f32_16x16x32_bf16(wzA[0], hb[0], zA, 0, 0, 0);
    rA = __builtin_amdgcn_mfma_f32_16x16x32_bf16(wrA[0], hb[0], rA, 0, 0, 0);
    zB = __builtin_amdgcn_mfma_f32_16x16x32_bf16(wzA[2], hb[2], zB, 0, 0, 0);
    rB = __builtin_amdgcn_mfma_f32_16x16x32_bf16(wrA[2], hb[2], rB, 0, 0, 0);
    zA = __builtin_amdgcn_mfma_f32_16x16x32_bf16(wzA[1], hb[1], zA, 0, 0, 0);
    rA = __builtin_amdgcn_mfma_f32_16x16x32_bf16(wrA[1], hb[1], rA, 0, 0, 0);
    zB = __builtin_amdgcn_mfma_f32_16x16x32_bf16(wzA[3], hb[3], zB, 0, 0, 0);
    rB = __builtin_amdgcn_mfma_f32_16x16x32_bf16(wrA[3], hb[3], rB, 0, 0, 0);

    // gates (all in registers); rh^T -> LDS via one b64 write
    float zp[4];
    bf16x4 rhv;
    #pragma unroll
    for (int q = 0; q < 4; ++q) {
      zp[q] = av * fast_sigmoid(zA[q] + zB[q]);
      float rr = fast_sigmoid(rA[q] + rB[q]);
      rhv[q] = (__bf16)(rr * hreg[q]);
    }
    *(bf16x4*)&lds_rh[l15 * LDH_STRIDE + myhid] = rhv;
    barrier_lds();  // B1: rh^T visible; global prefetch in flight

    // phase 2: h~T = preact + Wh_h x rh^T (split-k depth 2)
    bf16x8 rb[4];
    #pragma unroll
    for (int kt = 0; kt < 4; ++kt)
      rb[kt] = *(const bf16x8*)&lds_rh[l15 * LDH_STRIDE + kt * 32 + lk * 8];

    f32x4 hA, hB;
    { f32x4 a; a[0]=phv[0]; a[1]=phv[1]; a[2]=phv[2]; a[3]=phv[3]; hA = a; }
    { f32x4 z; z[0]=0.f; z[1]=0.f; z[2]=0.f; z[3]=0.f; hB = z; }
    hA = __builtin_amdgcn_mfma_f32_16x16x32_bf16(whA[0], rb[0], hA, 0, 0, 0);
    hB = __builtin_amdgcn_mfma_f32_16x16x32_bf16(whA[2], rb[2], hB, 0, 0, 0);
    hA = __builtin_amdgcn_mfma_f32_16x16x32_bf16(whA[1], rb[1], hA, 0, 0, 0);
    hB = __builtin_amdgcn_mfma_f32_16x16x32_bf16(whA[3], rb[3], hB, 0, 0, 0);

    // update h (registers) ; h^T -> LDS via one b64 write
    bf16x4 hbv;
    #pragma unroll
    for (int q = 0; q < 4; ++q) {
      float ht = fast_tanh(hA[q] + hB[q]);
      float hn = __builtin_fmaf(zp[q], ht - hreg[q], hreg[q]);
      hreg[q] = hn;
      hbv[q] = (__bf16)hn;
    }
    *(bf16x4*)&lds_h[l15 * LDH_STRIDE + myhid] = hbv;
    barrier_lds();  // B2: h^T visible for next phase 1
  }

  // ---- epilogue: contiguous float4 store ----
  float4 o;
  o.x = hreg[0]; o.y = hreg[1]; o.z = hreg[2]; o.w = hreg[3];
  *(float4*)&out[(size_t)(r0 + l15) * H_DIM + myhid] = o;
}

// ---------------------------------------------------------------------------
// Fallback: proven single-kernel version (round 2).
// ---------------------------------------------------------------------------
__global__ __launch_bounds__(256, 1)
void augru_kernel(const float* __restrict__ inputs,
                  const float* __restrict__ attn,
                  const float* __restrict__ Wz, const float* __restrict__ bz,
                  const float* __restrict__ Wr, const float* __restrict__ br,
                  const float* __restrict__ Wh, const float* __restrict__ bh,
                  float* __restrict__ out) {
  __shared__ __align__(16) short lds_a[16 * LDA_STRIDE];
  __shared__ float lds_att[16 * LATT_STRIDE];

  const int tid = threadIdx.x;
  const int w   = tid >> 6;
  const int l   = tid & 63;
  const int l15 = l & 15;
  const int lk  = l >> 4;
  const int r0  = blockIdx.x * 16;

  for (int idx = tid; idx < 16 * T_N; idx += 256) {
    int row = idx / T_N, t = idx - row * T_N;
    lds_att[row * LATT_STRIDE + t] = attn[(size_t)(r0 + row) * T_N + t];
  }
  for (int idx = tid; idx < 16 * H_DIM; idx += 256) {
    int row = idx >> 7, c = idx & 127;
    lds_a[row * LDA_STRIDE + c] = 0;
  }

  bf16x8 w1[32];
  float  bias1[4];
  #pragma unroll
  for (int ct = 0; ct < 4; ++ct) {
    int n = w * 32 + (ct & 1) * 16 + l15;
    const float* Wp; float bv;
    if (ct < 2) { Wp = Wz + (size_t)n * 256; bv = bz[n]; }
    else        { Wp = Wr + (size_t)n * 256; bv = br[n]; }
    bias1[ct] = bv;
    #pragma unroll
    for (int kt = 0; kt < 8; ++kt) {
      const float* p = Wp + kt * 32 + lk * 8;
      w1[ct * 8 + kt] = pack8(*(const float4*)p, *(const float4*)(p + 4));
    }
  }
  bf16x8 w2[16];
  float  bias2[2];
  #pragma unroll
  for (int ct = 0; ct < 2; ++ct) {
    int n = w * 32 + ct * 16 + l15;
    bias2[ct] = bh[n];
    const float* Wp = Wh + (size_t)n * 256;
    #pragma unroll
    for (int kt = 0; kt < 8; ++kt) {
      const float* p = Wp + kt * 32 + lk * 8;
      w2[ct * 8 + kt] = pack8(*(const float4*)p, *(const float4*)(p + 4));
    }
  }

  float hreg[2][4];
  #pragma unroll
  for (int ct = 0; ct < 2; ++ct)
    #pragma unroll
    for (int q = 0; q < 4; ++q) hreg[ct][q] = 0.0f;

  const float* xbase = inputs + (size_t)(r0 + l15) * (T_N * I_DIM);
  bf16x8 xfrag[4];
  #pragma unroll
  for (int kt = 0; kt < 4; ++kt) {
    const float* p = xbase + kt * 32 + lk * 8;
    xfrag[kt] = pack8(*(const float4*)p, *(const float4*)(p + 4));
  }

  __syncthreads();

  float4 xr0[4], xr1[4];
  for (int t = 0; t < T_N; ++t) {
    if (t + 1 < T_N) {
      #pragma unroll
      for (int kt = 0; kt < 4; ++kt) {
        const float* p = xbase + (size_t)(t + 1) * I_DIM + kt * 32 + lk * 8;
        xr0[kt] = *(const float4*)p;
        xr1[kt] = *(const float4*)(p + 4);
      }
    }
    bf16x8 hfrag[4];
    #pragma unroll
    for (int kt = 0; kt < 4; ++kt)
      hfrag[kt] = *(const bf16x8*)&lds_a[l15 * LDA_STRIDE + kt * 32 + lk * 8];
    float av[4];
    #pragma unroll
    for (int q = 0; q < 4; ++q) av[q] = lds_att[(lk * 4 + q) * LATT_STRIDE + t];

    f32x4 acc[4];
    #pragma unroll
    for (int ct = 0; ct < 4; ++ct) {
      f32x4 a; a[0] = bias1[ct]; a[1] = bias1[ct]; a[2] = bias1[ct]; a[3] = bias1[ct];
      acc[ct] = a;
    }
    #pragma unroll
    for (int kt = 0; kt < 4; ++kt)
      #pragma unroll
      for (int ct = 0; ct < 4; ++ct)
        acc[ct] = __builtin_amdgcn_mfma_f32_16x16x32_bf16(xfrag[kt], w1[ct * 8 + kt], acc[ct], 0, 0, 0);

    f32x4 acc2[2];
    #pragma unroll
    for (int ct = 0; ct < 2; ++ct) {
      f32x4 a; a[0] = bias2[ct]; a[1] = bias2[ct]; a[2] = bias2[ct]; a[3] = bias2[ct];
      acc2[ct] = a;
    }
    #pragma unroll
    for (int kt = 0; kt < 4; ++kt)
      #pragma unroll
      for (int ct = 0; ct < 2; ++ct)
        acc2[ct] = __builtin_amdgcn_mfma_f32_16x16x32_bf16(xfrag[kt], w2[ct * 8 + kt], acc2[ct], 0, 0, 0);

    #pragma unroll
    for (int kt = 0; kt < 4; ++kt)
      #pragma unroll
      for (int ct = 0; ct < 4; ++ct)
        acc[ct] = __builtin_amdgcn_mfma_f32_16x16x32_bf16(hfrag[kt], w1[ct * 8 + 4 + kt], acc[ct], 0, 0, 0);

    float zp[2][4];
    #pragma unroll
    for (int ct = 0; ct < 2; ++ct) {
      int col = w * 32 + ct * 16 + l15;
      #pragma unroll
      for (int q = 0; q < 4; ++q) {
        int row = lk * 4 + q;
        zp[ct][q] = av[q] * fast_sigmoid(acc[ct][q]);
        float rr = fast_sigmoid(acc[2 + ct][q]);
        __bf16 rhb = (__bf16)(rr * hreg[ct][q]);
        lds_a[row * LDA_STRIDE + 128 + col] = __builtin_bit_cast(short, rhb);
      }
    }
    barrier_lds();

    bf16x8 rfrag[4];
    #pragma unroll
    for (int kt = 0; kt < 4; ++kt)
      rfrag[kt] = *(const bf16x8*)&lds_a[l15 * LDA_STRIDE + 128 + kt * 32 + lk * 8];
    #pragma unroll
    for (int kt = 0; kt < 4; ++kt)
      #pragma unroll
      for (int ct = 0; ct < 2; ++ct)
        acc2[ct] = __builtin_amdgcn_mfma_f32_16x16x32_bf16(rfrag[kt], w2[ct * 8 + 4 + kt], acc2[ct], 0, 0, 0);

    if (t + 1 < T_N) {
      #pragma unroll
      for (int kt = 0; kt < 4; ++kt)
        xfrag[kt] = pack8(xr0[kt], xr1[kt]);
    }

    #pragma unroll
    for (int ct = 0; ct < 2; ++ct) {
      int col = w * 32 + ct * 16 + l15;
      #pragma unroll
      for (int q = 0; q < 4; ++q) {
        int row = lk * 4 + q;
        float ht = fast_tanh(acc2[ct][q]);
        float ho = hreg[ct][q];
        float hn = __builtin_fmaf(zp[ct][q], ht - ho, ho);
        hreg[ct][q] = hn;
        __bf16 hb = (__bf16)hn;
        lds_a[row * LDA_STRIDE + col] = __builtin_bit_cast(short, hb);
      }
    }
    barrier_lds();
  }

  #pragma unroll
  for (int ct = 0; ct < 2; ++ct) {
    int col = w * 32 + ct * 16 + l15;
    #pragma unroll
    for (int q = 0; q < 4; ++q) {
      int row = lk * 4 + q;
      out[(size_t)(r0 + row) * H_DIM + col] = hreg[ct][q];
    }
  }
}

extern "C" void kernel_launch(void* const* d_in, const int* in_sizes, int n_in,
                              void* d_out, int out_size, void* d_ws, size_t ws_size,
                              hipStream_t stream) {
  (void)in_sizes; (void)n_in; (void)out_size;
  const float* inputs = (const float*)d_in[0];
  const float* attn   = (const float*)d_in[1];
  const float* Wz     = (const float*)d_in[2];
  const float* bz     = (const float*)d_in[3];
  const float* Wr     = (const float*)d_in[4];
  const float* br     = (const float*)d_in[5];
  const float* Wh     = (const float*)d_in[6];
  const float* bh     = (const float*)d_in[7];
  float* out = (float*)d_out;

  if (ws_size >= PRE_BYTES) {
    char* pre = (char*)d_ws;
    xproj_kernel<<<NBLK * (T_N / TCHUNK), 256, 0, stream>>>(inputs, Wz, bz, Wr, br, Wh, bh, pre);
    augru_rec_kernel<<<NBLK, 512, 0, stream>>>(pre, attn, Wz, Wr, Wh, out);
  } else {
    augru_kernel<<<NBLK, 256, 0, stream>>>(inputs, attn, Wz, bz, Wr, br, Wh, bh, out);
  }
}

// Round 7
// 307.592 us; speedup vs baseline: 1.1036x; 1.1036x over previous
//
#include <hip/hip_runtime.h>

// AUGRU, round 6 resubmit (R6 bench died on infra: UnresponsiveContainer).
//  Pass 1 (xcast): f32 -> bf16 cast of inputs (same [B][T][I] layout) into d_ws.
//  Pass 2 (fused): 64 blocks x 8 waves, transposed orientation
//       D[hidden][batch] = W-frag(A) x (x|h|rh)^T-frag(B).
//     Per step: phase1 z,r = (bias + Wx*x, in f32 accs) + Wh*h ; gates in regs;
//     rh -> LDS b64; B1; phase2 h~ ; x-part MFMAs for t+1 overlap rb reads;
//     update h in regs; h -> LDS b64; B2. Preacts never leave registers.
// Fallback: proven single-kernel (R2) if ws too small.

#define T_N   200
#define I_DIM 128
#define H_DIM 128
#define NBLK  64

typedef float  f32x4  __attribute__((ext_vector_type(4)));
typedef __bf16 bf16x4 __attribute__((ext_vector_type(4)));
typedef __bf16 bf16x8 __attribute__((ext_vector_type(8)));

#define LDH_STRIDE 136   // shorts per batch row: 128 + 8 pad
#define XCAST_BYTES ((size_t)1024 * T_N * I_DIM * 2)   // 52,428,800

// fallback LDS
#define LDA_STRIDE 264
#define LATT_STRIDE 201

__device__ __forceinline__ float fast_sigmoid(float x) {
  float e = __builtin_amdgcn_exp2f(-1.4426950408889634f * x);
  return __builtin_amdgcn_rcpf(1.0f + e);
}
__device__ __forceinline__ float fast_tanh(float x) {
  float e = __builtin_amdgcn_exp2f(2.8853900817779268f * x);
  return 1.0f - 2.0f * __builtin_amdgcn_rcpf(1.0f + e);
}
__device__ __forceinline__ void barrier_lds() {
  asm volatile("s_waitcnt lgkmcnt(0)\n\ts_barrier" ::: "memory");
}
__device__ __forceinline__ bf16x8 pack8(float4 a, float4 b) {
  bf16x8 t;
  t[0] = (__bf16)a.x; t[1] = (__bf16)a.y; t[2] = (__bf16)a.z; t[3] = (__bf16)a.w;
  t[4] = (__bf16)b.x; t[5] = (__bf16)b.y; t[6] = (__bf16)b.z; t[7] = (__bf16)b.w;
  return t;
}

// ---------------------------------------------------------------------------
// Pass 1: cast inputs f32 -> bf16, same layout. 26,214,400 elems.
// ---------------------------------------------------------------------------
__global__ __launch_bounds__(256, 4)
void xcast_kernel(const float* __restrict__ in, __bf16* __restrict__ outb) {
  size_t i = ((size_t)blockIdx.x * 256 + threadIdx.x) * 8;
  float4 a = *(const float4*)(in + i);
  float4 b = *(const float4*)(in + i + 4);
  *(bf16x8*)(outb + i) = pack8(a, b);
}

// ---------------------------------------------------------------------------
// Pass 2: fused recurrence. grid = 64 blocks, 512 threads (8 waves).
// ---------------------------------------------------------------------------
__global__ __launch_bounds__(512, 1)
void augru_fused_kernel(const __bf16* __restrict__ xb,
                        const float* __restrict__ attn,
                        const float* __restrict__ Wz, const float* __restrict__ bz,
                        const float* __restrict__ Wr, const float* __restrict__ br,
                        const float* __restrict__ Wh, const float* __restrict__ bh,
                        float* __restrict__ out) {
  __shared__ __align__(16) short lds_h [16 * LDH_STRIDE];  // hT  [batch][hidden]
  __shared__ __align__(16) short lds_rh[16 * LDH_STRIDE];  // rhT [batch][hidden]
  __shared__ float lds_att[T_N * 16];                      // [t][batch]

  const int tid   = threadIdx.x;
  const int w     = tid >> 6;
  const int l     = tid & 63;
  const int l15   = l & 15;
  const int lk    = l >> 4;
  const int r0    = blockIdx.x * 16;
  const int myhid = w * 16 + lk * 4;

  // ---- prologue: attention -> LDS, zero h ----
  for (int idx = tid; idx < T_N * 16; idx += 512) {
    int t = idx >> 4, b = idx & 15;
    lds_att[idx] = attn[(size_t)(r0 + b) * T_N + t];
  }
  for (int idx = tid; idx < 16 * LDH_STRIDE; idx += 512) lds_h[idx] = 0;

  // ---- weights -> A-frags. row = hidden w*16 + l15. x-part k=0..127, h-part 128..255 ----
  bf16x8 wzX[4], wrX[4], whX[4], wzH[4], wrH[4], whH[4];
  {
    const float* pz = Wz + (size_t)(w * 16 + l15) * 256;
    const float* pr = Wr + (size_t)(w * 16 + l15) * 256;
    const float* ph = Wh + (size_t)(w * 16 + l15) * 256;
    #pragma unroll
    for (int kt = 0; kt < 4; ++kt) {
      const float* a;
      a = pz + kt * 32 + lk * 8;       wzX[kt] = pack8(*(const float4*)a, *(const float4*)(a + 4));
      a = pz + 128 + kt * 32 + lk * 8; wzH[kt] = pack8(*(const float4*)a, *(const float4*)(a + 4));
      a = pr + kt * 32 + lk * 8;       wrX[kt] = pack8(*(const float4*)a, *(const float4*)(a + 4));
      a = pr + 128 + kt * 32 + lk * 8; wrH[kt] = pack8(*(const float4*)a, *(const float4*)(a + 4));
      a = ph + kt * 32 + lk * 8;       whX[kt] = pack8(*(const float4*)a, *(const float4*)(a + 4));
      a = ph + 128 + kt * 32 + lk * 8; whH[kt] = pack8(*(const float4*)a, *(const float4*)(a + 4));
    }
  }
  // biases for this thread's 4 hidden rows
  f32x4 bias4[3];
  {
    float4 b0 = *(const float4*)&bz[myhid];
    float4 b1 = *(const float4*)&br[myhid];
    float4 b2 = *(const float4*)&bh[myhid];
    bias4[0][0]=b0.x; bias4[0][1]=b0.y; bias4[0][2]=b0.z; bias4[0][3]=b0.w;
    bias4[1][0]=b1.x; bias4[1][1]=b1.y; bias4[1][2]=b1.z; bias4[1][3]=b1.w;
    bias4[2][0]=b2.x; bias4[2][1]=b2.y; bias4[2][2]=b2.z; bias4[2][3]=b2.w;
  }

  float hreg[4];
  #pragma unroll
  for (int q = 0; q < 4; ++q) hreg[q] = 0.0f;

  // x^T frag base for this lane: x[r0+l15][t][kt*32+lk*8 .. +8] bf16
  const __bf16* xrow = xb + ((size_t)(r0 + l15) * T_N) * I_DIM + lk * 8;

  // ---- preact accumulators (f32, never materialized) ----
  f32x4 accP[2][3];
  {
    bf16x8 xf0[4];
    #pragma unroll
    for (int kt = 0; kt < 4; ++kt)
      xf0[kt] = *(const bf16x8*)(xrow + kt * 32);   // t = 0
    #pragma unroll
    for (int g = 0; g < 3; ++g) accP[0][g] = bias4[g];
    #pragma unroll
    for (int kt = 0; kt < 4; ++kt) {
      accP[0][0] = __builtin_amdgcn_mfma_f32_16x16x32_bf16(wzX[kt], xf0[kt], accP[0][0], 0, 0, 0);
      accP[0][1] = __builtin_amdgcn_mfma_f32_16x16x32_bf16(wrX[kt], xf0[kt], accP[0][1], 0, 0, 0);
      accP[0][2] = __builtin_amdgcn_mfma_f32_16x16x32_bf16(whX[kt], xf0[kt], accP[0][2], 0, 0, 0);
    }
  }

  __syncthreads();

#define STEP_BODY(T_CUR, CUR, NXT)                                              \
  {                                                                             \
    const int t_ = (T_CUR);                                                     \
    /* h^T frags */                                                             \
    bf16x8 hb[4];                                                               \
    _Pragma("unroll")                                                           \
    for (int kt = 0; kt < 4; ++kt)                                              \
      hb[kt] = *(const bf16x8*)&lds_h[l15 * LDH_STRIDE + kt * 32 + lk * 8];     \
    /* x frags for t+1 (global, L3-hot; consumed after B1) */                   \
    bf16x8 xf[4];                                                               \
    if (t_ + 1 < T_N) {                                                         \
      const __bf16* xp = xrow + (size_t)(t_ + 1) * I_DIM;                       \
      _Pragma("unroll")                                                         \
      for (int kt = 0; kt < 4; ++kt) xf[kt] = *(const bf16x8*)(xp + kt * 32);   \
    }                                                                           \
    const float av = lds_att[t_ * 16 + l15];                                    \
    /* phase1: z,r (split-k depth 2) */                                         \
    f32x4 zA = accP[CUR][0], rA = accP[CUR][1], zB, rB;                         \
    zB[0]=0.f; zB[1]=0.f; zB[2]=0.f; zB[3]=0.f; rB = zB;                        \
    zA = __builtin_amdgcn_mfma_f32_16x16x32_bf16(wzH[0], hb[0], zA, 0, 0, 0);   \
    rA = __builtin_amdgcn_mfma_f32_16x16x32_bf16(wrH[0], hb[0], rA, 0, 0, 0);   \
    zB = __builtin_amdgcn_mfma_f32_16x16x32_bf16(wzH[2], hb[2], zB, 0, 0, 0);   \
    rB = __builtin_amdgcn_mfma_f32_16x16x32_bf16(wrH[2], hb[2], rB, 0, 0, 0);   \
    zA = __builtin_amdgcn_mfma_f32_16x16x32_bf16(wzH[1], hb[1], zA, 0, 0, 0);   \
    rA = __builtin_amdgcn_mfma_f32_16x16x32_bf16(wrH[1], hb[1], rA, 0, 0, 0);   \
    zB = __builtin_amdgcn_mfma_f32_16x16x32_bf16(wzH[3], hb[3], zB, 0, 0, 0);   \
    rB = __builtin_amdgcn_mfma_f32_16x16x32_bf16(wrH[3], hb[3], rB, 0, 0, 0);   \
    /* gates in registers; rh -> LDS (one b64) */                               \
    float zp[4]; bf16x4 rhv;                                                    \
    _Pragma("unroll")                                                           \
    for (int q = 0; q < 4; ++q) {                                               \
      zp[q] = av * fast_sigmoid(zA[q] + zB[q]);                                 \
      float rr = fast_sigmoid(rA[q] + rB[q]);                                   \
      rhv[q] = (__bf16)(rr * hreg[q]);                                          \
    }                                                                           \
    *(bf16x4*)&lds_rh[l15 * LDH_STRIDE + myhid] = rhv;                          \
    barrier_lds();                                                              \
    /* rb frags; x-part MFMAs for t+1 overlap the read latency */               \
    bf16x8 rb[4];                                                               \
    _Pragma("unroll")                                                           \
    for (int kt = 0; kt < 4; ++kt)                                              \
      rb[kt] = *(const bf16x8*)&lds_rh[l15 * LDH_STRIDE + kt * 32 + lk * 8];    \
    if (t_ + 1 < T_N) {                                                         \
      _Pragma("unroll")                                                         \
      for (int g = 0; g < 3; ++g) accP[NXT][g] = bias4[g];                      \
      _Pragma("unroll")                                                         \
      for (int kt = 0; kt < 4; ++kt) {                                          \
        accP[NXT][0] = __builtin_amdgcn_mfma_f32_16x16x32_bf16(wzX[kt], xf[kt], accP[NXT][0], 0, 0, 0); \
        accP[NXT][1] = __builtin_amdgcn_mfma_f32_16x16x32_bf16(wrX[kt], xf[kt], accP[NXT][1], 0, 0, 0); \
        accP[NXT][2] = __builtin_amdgcn_mfma_f32_16x16x32_bf16(whX[kt], xf[kt], accP[NXT][2], 0, 0, 0); \
      }                                                                         \
    }                                                                           \
    /* phase2: h~ (split-k depth 2) */                                          \
    f32x4 hA = accP[CUR][2], hB;                                                \
    hB[0]=0.f; hB[1]=0.f; hB[2]=0.f; hB[3]=0.f;                                 \
    hA = __builtin_amdgcn_mfma_f32_16x16x32_bf16(whH[0], rb[0], hA, 0, 0, 0);   \
    hB = __builtin_amdgcn_mfma_f32_16x16x32_bf16(whH[2], rb[2], hB, 0, 0, 0);   \
    hA = __builtin_amdgcn_mfma_f32_16x16x32_bf16(whH[1], rb[1], hA, 0, 0, 0);   \
    hB = __builtin_amdgcn_mfma_f32_16x16x32_bf16(whH[3], rb[3], hB, 0, 0, 0);   \
    /* update h */                                                              \
    bf16x4 hbv;                                                                 \
    _Pragma("unroll")                                                           \
    for (int q = 0; q < 4; ++q) {                                               \
      float ht = fast_tanh(hA[q] + hB[q]);                                      \
      float hn = __builtin_fmaf(zp[q], ht - hreg[q], hreg[q]);                  \
      hreg[q] = hn;                                                             \
      hbv[q] = (__bf16)hn;                                                      \
    }                                                                           \
    *(bf16x4*)&lds_h[l15 * LDH_STRIDE + myhid] = hbv;                           \
    barrier_lds();                                                              \
  }

  for (int tt = 0; tt < T_N; tt += 2) {
    STEP_BODY(tt,     0, 1)
    STEP_BODY(tt + 1, 1, 0)
  }
#undef STEP_BODY

  // ---- epilogue ----
  float4 o;
  o.x = hreg[0]; o.y = hreg[1]; o.z = hreg[2]; o.w = hreg[3];
  *(float4*)&out[(size_t)(r0 + l15) * H_DIM + myhid] = o;
}

// ---------------------------------------------------------------------------
// Fallback: proven single-kernel version (round 2, 410 us).
// ---------------------------------------------------------------------------
__global__ __launch_bounds__(256, 1)
void augru_kernel(const float* __restrict__ inputs,
                  const float* __restrict__ attn,
                  const float* __restrict__ Wz, const float* __restrict__ bz,
                  const float* __restrict__ Wr, const float* __restrict__ br,
                  const float* __restrict__ Wh, const float* __restrict__ bh,
                  float* __restrict__ out) {
  __shared__ __align__(16) short lds_a[16 * LDA_STRIDE];
  __shared__ float lds_att[16 * LATT_STRIDE];

  const int tid = threadIdx.x;
  const int w   = tid >> 6;
  const int l   = tid & 63;
  const int l15 = l & 15;
  const int lk  = l >> 4;
  const int r0  = blockIdx.x * 16;

  for (int idx = tid; idx < 16 * T_N; idx += 256) {
    int row = idx / T_N, t = idx - row * T_N;
    lds_att[row * LATT_STRIDE + t] = attn[(size_t)(r0 + row) * T_N + t];
  }
  for (int idx = tid; idx < 16 * H_DIM; idx += 256) {
    int row = idx >> 7, c = idx & 127;
    lds_a[row * LDA_STRIDE + c] = 0;
  }

  bf16x8 w1[32];
  float  bias1[4];
  #pragma unroll
  for (int ct = 0; ct < 4; ++ct) {
    int n = w * 32 + (ct & 1) * 16 + l15;
    const float* Wp; float bv;
    if (ct < 2) { Wp = Wz + (size_t)n * 256; bv = bz[n]; }
    else        { Wp = Wr + (size_t)n * 256; bv = br[n]; }
    bias1[ct] = bv;
    #pragma unroll
    for (int kt = 0; kt < 8; ++kt) {
      const float* p = Wp + kt * 32 + lk * 8;
      w1[ct * 8 + kt] = pack8(*(const float4*)p, *(const float4*)(p + 4));
    }
  }
  bf16x8 w2[16];
  float  bias2[2];
  #pragma unroll
  for (int ct = 0; ct < 2; ++ct) {
    int n = w * 32 + ct * 16 + l15;
    bias2[ct] = bh[n];
    const float* Wp = Wh + (size_t)n * 256;
    #pragma unroll
    for (int kt = 0; kt < 8; ++kt) {
      const float* p = Wp + kt * 32 + lk * 8;
      w2[ct * 8 + kt] = pack8(*(const float4*)p, *(const float4*)(p + 4));
    }
  }

  float hreg[2][4];
  #pragma unroll
  for (int ct = 0; ct < 2; ++ct)
    #pragma unroll
    for (int q = 0; q < 4; ++q) hreg[ct][q] = 0.0f;

  const float* xbase = inputs + (size_t)(r0 + l15) * (T_N * I_DIM);
  bf16x8 xfrag[4];
  #pragma unroll
  for (int kt = 0; kt < 4; ++kt) {
    const float* p = xbase + kt * 32 + lk * 8;
    xfrag[kt] = pack8(*(const float4*)p, *(const float4*)(p + 4));
  }

  __syncthreads();

  float4 xr0[4], xr1[4];
  for (int t = 0; t < T_N; ++t) {
    if (t + 1 < T_N) {
      #pragma unroll
      for (int kt = 0; kt < 4; ++kt) {
        const float* p = xbase + (size_t)(t + 1) * I_DIM + kt * 32 + lk * 8;
        xr0[kt] = *(const float4*)p;
        xr1[kt] = *(const float4*)(p + 4);
      }
    }
    bf16x8 hfrag[4];
    #pragma unroll
    for (int kt = 0; kt < 4; ++kt)
      hfrag[kt] = *(const bf16x8*)&lds_a[l15 * LDA_STRIDE + kt * 32 + lk * 8];
    float av[4];
    #pragma unroll
    for (int q = 0; q < 4; ++q) av[q] = lds_att[(lk * 4 + q) * LATT_STRIDE + t];

    f32x4 acc[4];
    #pragma unroll
    for (int ct = 0; ct < 4; ++ct) {
      f32x4 a; a[0] = bias1[ct]; a[1] = bias1[ct]; a[2] = bias1[ct]; a[3] = bias1[ct];
      acc[ct] = a;
    }
    #pragma unroll
    for (int kt = 0; kt < 4; ++kt)
      #pragma unroll
      for (int ct = 0; ct < 4; ++ct)
        acc[ct] = __builtin_amdgcn_mfma_f32_16x16x32_bf16(xfrag[kt], w1[ct * 8 + kt], acc[ct], 0, 0, 0);

    f32x4 acc2[2];
    #pragma unroll
    for (int ct = 0; ct < 2; ++ct) {
      f32x4 a; a[0] = bias2[ct]; a[1] = bias2[ct]; a[2] = bias2[ct]; a[3] = bias2[ct];
      acc2[ct] = a;
    }
    #pragma unroll
    for (int kt = 0; kt < 4; ++kt)
      #pragma unroll
      for (int ct = 0; ct < 2; ++ct)
        acc2[ct] = __builtin_amdgcn_mfma_f32_16x16x32_bf16(xfrag[kt], w2[ct * 8 + kt], acc2[ct], 0, 0, 0);

    #pragma unroll
    for (int kt = 0; kt < 4; ++kt)
      #pragma unroll
      for (int ct = 0; ct < 4; ++ct)
        acc[ct] = __builtin_amdgcn_mfma_f32_16x16x32_bf16(hfrag[kt], w1[ct * 8 + 4 + kt], acc[ct], 0, 0, 0);

    float zp[2][4];
    #pragma unroll
    for (int ct = 0; ct < 2; ++ct) {
      int col = w * 32 + ct * 16 + l15;
      #pragma unroll
      for (int q = 0; q < 4; ++q) {
        int row = lk * 4 + q;
        zp[ct][q] = av[q] * fast_sigmoid(acc[ct][q]);
        float rr = fast_sigmoid(acc[2 + ct][q]);
        __bf16 rhb = (__bf16)(rr * hreg[ct][q]);
        lds_a[row * LDA_STRIDE + 128 + col] = __builtin_bit_cast(short, rhb);
      }
    }
    barrier_lds();

    bf16x8 rfrag[4];
    #pragma unroll
    for (int kt = 0; kt < 4; ++kt)
      rfrag[kt] = *(const bf16x8*)&lds_a[l15 * LDA_STRIDE + 128 + kt * 32 + lk * 8];
    #pragma unroll
    for (int kt = 0; kt < 4; ++kt)
      #pragma unroll
      for (int ct = 0; ct < 2; ++ct)
        acc2[ct] = __builtin_amdgcn_mfma_f32_16x16x32_bf16(rfrag[kt], w2[ct * 8 + 4 + kt], acc2[ct], 0, 0, 0);

    if (t + 1 < T_N) {
      #pragma unroll
      for (int kt = 0; kt < 4; ++kt)
        xfrag[kt] = pack8(xr0[kt], xr1[kt]);
    }

    #pragma unroll
    for (int ct = 0; ct < 2; ++ct) {
      int col = w * 32 + ct * 16 + l15;
      #pragma unroll
      for (int q = 0; q < 4; ++q) {
        int row = lk * 4 + q;
        float ht = fast_tanh(acc2[ct][q]);
        float ho = hreg[ct][q];
        float hn = __builtin_fmaf(zp[ct][q], ht - ho, ho);
        hreg[ct][q] = hn;
        __bf16 hb = (__bf16)hn;
        lds_a[row * LDA_STRIDE + col] = __builtin_bit_cast(short, hb);
      }
    }
    barrier_lds();
  }

  #pragma unroll
  for (int ct = 0; ct < 2; ++ct) {
    int col = w * 32 + ct * 16 + l15;
    #pragma unroll
    for (int q = 0; q < 4; ++q) {
      int row = lk * 4 + q;
      out[(size_t)(r0 + row) * H_DIM + col] = hreg[ct][q];
    }
  }
}

extern "C" void kernel_launch(void* const* d_in, const int* in_sizes, int n_in,
                              void* d_out, int out_size, void* d_ws, size_t ws_size,
                              hipStream_t stream) {
  (void)in_sizes; (void)n_in; (void)out_size;
  const float* inputs = (const float*)d_in[0];
  const float* attn   = (const float*)d_in[1];
  const float* Wz     = (const float*)d_in[2];
  const float* bz     = (const float*)d_in[3];
  const float* Wr     = (const float*)d_in[4];
  const float* br     = (const float*)d_in[5];
  const float* Wh     = (const float*)d_in[6];
  const float* bh     = (const float*)d_in[7];
  float* out = (float*)d_out;

  if (ws_size >= XCAST_BYTES) {
    __bf16* xb = (__bf16*)d_ws;
    const size_t nelem = (size_t)1024 * T_N * I_DIM;          // 26,214,400
    xcast_kernel<<<(int)(nelem / (256 * 8)), 256, 0, stream>>>(inputs, xb);
    augru_fused_kernel<<<NBLK, 512, 0, stream>>>(xb, attn, Wz, bz, Wr, br, Wh, bh, out);
  } else {
    augru_kernel<<<NBLK, 256, 0, stream>>>(inputs, attn, Wz, bz, Wr, br, Wh, bh, out);
  }
}

// Round 8
// 301.663 us; speedup vs baseline: 1.1253x; 1.0197x over previous
//
#include <hip/hip_runtime.h>

// AUGRU, round 8: fused recurrence, scheduling fix over R7.
//  - x frag loads prefetched 2 steps ahead (ring xA/xB) -> vmcnt never stalls.
//  - x-part MFMAs placed AFTER phase2 MFMA issue -> can't block the chain.
//  Pass 1 (xcast): f32 -> bf16 cast of inputs into d_ws.
//  Pass 2 (fused): 64 blocks x 8 waves, transposed D[hidden][batch] =
//      W(A) x (x|h|rh)^T(B); preacts live in f32 accumulators only.
// Fallback: proven single-kernel (R2) if ws too small.

#define T_N   200
#define I_DIM 128
#define H_DIM 128
#define NBLK  64

typedef float  f32x4  __attribute__((ext_vector_type(4)));
typedef __bf16 bf16x4 __attribute__((ext_vector_type(4)));
typedef __bf16 bf16x8 __attribute__((ext_vector_type(8)));

#define LDH_STRIDE 136   // shorts per batch row: 128 + 8 pad
#define XCAST_BYTES ((size_t)1024 * T_N * I_DIM * 2)   // 52,428,800

// fallback LDS
#define LDA_STRIDE 264
#define LATT_STRIDE 201

__device__ __forceinline__ float fast_sigmoid(float x) {
  float e = __builtin_amdgcn_exp2f(-1.4426950408889634f * x);
  return __builtin_amdgcn_rcpf(1.0f + e);
}
__device__ __forceinline__ float fast_tanh(float x) {
  float e = __builtin_amdgcn_exp2f(2.8853900817779268f * x);
  return 1.0f - 2.0f * __builtin_amdgcn_rcpf(1.0f + e);
}
__device__ __forceinline__ void barrier_lds() {
  asm volatile("s_waitcnt lgkmcnt(0)\n\ts_barrier" ::: "memory");
}
__device__ __forceinline__ bf16x8 pack8(float4 a, float4 b) {
  bf16x8 t;
  t[0] = (__bf16)a.x; t[1] = (__bf16)a.y; t[2] = (__bf16)a.z; t[3] = (__bf16)a.w;
  t[4] = (__bf16)b.x; t[5] = (__bf16)b.y; t[6] = (__bf16)b.z; t[7] = (__bf16)b.w;
  return t;
}

// ---------------------------------------------------------------------------
// Pass 1: cast inputs f32 -> bf16, same layout. 26,214,400 elems.
// ---------------------------------------------------------------------------
__global__ __launch_bounds__(256, 4)
void xcast_kernel(const float* __restrict__ in, __bf16* __restrict__ outb) {
  size_t i = ((size_t)blockIdx.x * 256 + threadIdx.x) * 8;
  float4 a = *(const float4*)(in + i);
  float4 b = *(const float4*)(in + i + 4);
  *(bf16x8*)(outb + i) = pack8(a, b);
}

// ---------------------------------------------------------------------------
// Pass 2: fused recurrence. grid = 64 blocks, 512 threads (8 waves).
// ---------------------------------------------------------------------------
__global__ __launch_bounds__(512, 1)
void augru_fused_kernel(const __bf16* __restrict__ xb,
                        const float* __restrict__ attn,
                        const float* __restrict__ Wz, const float* __restrict__ bz,
                        const float* __restrict__ Wr, const float* __restrict__ br,
                        const float* __restrict__ Wh, const float* __restrict__ bh,
                        float* __restrict__ out) {
  __shared__ __align__(16) short lds_h [16 * LDH_STRIDE];  // hT  [batch][hidden]
  __shared__ __align__(16) short lds_rh[16 * LDH_STRIDE];  // rhT [batch][hidden]
  __shared__ float lds_att[T_N * 16];                      // [t][batch]

  const int tid   = threadIdx.x;
  const int w     = tid >> 6;
  const int l     = tid & 63;
  const int l15   = l & 15;
  const int lk    = l >> 4;
  const int r0    = blockIdx.x * 16;
  const int myhid = w * 16 + lk * 4;

  // ---- prologue: attention -> LDS, zero h ----
  for (int idx = tid; idx < T_N * 16; idx += 512) {
    int t = idx >> 4, b = idx & 15;
    lds_att[idx] = attn[(size_t)(r0 + b) * T_N + t];
  }
  for (int idx = tid; idx < 16 * LDH_STRIDE; idx += 512) lds_h[idx] = 0;

  // ---- weights -> A-frags. row = hidden w*16 + l15 ----
  bf16x8 wzX[4], wrX[4], whX[4], wzH[4], wrH[4], whH[4];
  {
    const float* pz = Wz + (size_t)(w * 16 + l15) * 256;
    const float* pr = Wr + (size_t)(w * 16 + l15) * 256;
    const float* ph = Wh + (size_t)(w * 16 + l15) * 256;
    #pragma unroll
    for (int kt = 0; kt < 4; ++kt) {
      const float* a;
      a = pz + kt * 32 + lk * 8;       wzX[kt] = pack8(*(const float4*)a, *(const float4*)(a + 4));
      a = pz + 128 + kt * 32 + lk * 8; wzH[kt] = pack8(*(const float4*)a, *(const float4*)(a + 4));
      a = pr + kt * 32 + lk * 8;       wrX[kt] = pack8(*(const float4*)a, *(const float4*)(a + 4));
      a = pr + 128 + kt * 32 + lk * 8; wrH[kt] = pack8(*(const float4*)a, *(const float4*)(a + 4));
      a = ph + kt * 32 + lk * 8;       whX[kt] = pack8(*(const float4*)a, *(const float4*)(a + 4));
      a = ph + 128 + kt * 32 + lk * 8; whH[kt] = pack8(*(const float4*)a, *(const float4*)(a + 4));
    }
  }
  // biases for this thread's 4 hidden rows
  f32x4 bias4[3];
  {
    float4 b0 = *(const float4*)&bz[myhid];
    float4 b1 = *(const float4*)&br[myhid];
    float4 b2 = *(const float4*)&bh[myhid];
    bias4[0][0]=b0.x; bias4[0][1]=b0.y; bias4[0][2]=b0.z; bias4[0][3]=b0.w;
    bias4[1][0]=b1.x; bias4[1][1]=b1.y; bias4[1][2]=b1.z; bias4[1][3]=b1.w;
    bias4[2][0]=b2.x; bias4[2][1]=b2.y; bias4[2][2]=b2.z; bias4[2][3]=b2.w;
  }

  float hreg[4];
  #pragma unroll
  for (int q = 0; q < 4; ++q) hreg[q] = 0.0f;

  // x^T frag base for this lane
  const __bf16* xrow = xb + ((size_t)(r0 + l15) * T_N) * I_DIM + lk * 8;

  // ---- preact accumulators (f32, never materialized) ----
  f32x4 accP[2][3];
  {
    bf16x8 xf0[4];
    #pragma unroll
    for (int kt = 0; kt < 4; ++kt)
      xf0[kt] = *(const bf16x8*)(xrow + kt * 32);   // t = 0
    #pragma unroll
    for (int g = 0; g < 3; ++g) accP[0][g] = bias4[g];
    #pragma unroll
    for (int kt = 0; kt < 4; ++kt) {
      accP[0][0] = __builtin_amdgcn_mfma_f32_16x16x32_bf16(wzX[kt], xf0[kt], accP[0][0], 0, 0, 0);
      accP[0][1] = __builtin_amdgcn_mfma_f32_16x16x32_bf16(wrX[kt], xf0[kt], accP[0][1], 0, 0, 0);
      accP[0][2] = __builtin_amdgcn_mfma_f32_16x16x32_bf16(whX[kt], xf0[kt], accP[0][2], 0, 0, 0);
    }
  }

  // ---- x frag ring, 2 steps deep. xA holds x[1] for step 0. ----
  bf16x8 xA[4], xB[4];
  #pragma unroll
  for (int kt = 0; kt < 4; ++kt)
    xA[kt] = *(const bf16x8*)(xrow + (size_t)1 * I_DIM + kt * 32);

  __syncthreads();

// Step t: consume XC (= x[t+1]) into accP[NXT] AFTER phase2 issue;
//         issue loads for x[t+2] into XI at the top (2-step-ahead).
#define STEP_BODY(T_CUR, CUR, NXT, XC, XI)                                      \
  {                                                                             \
    const int t_ = (T_CUR);                                                     \
    /* issue x loads for t+2 (consumed next step; ~2 steps of cover) */         \
    if (t_ + 2 < T_N) {                                                         \
      const __bf16* xp2 = xrow + (size_t)(t_ + 2) * I_DIM;                      \
      _Pragma("unroll")                                                         \
      for (int kt = 0; kt < 4; ++kt) XI[kt] = *(const bf16x8*)(xp2 + kt * 32);  \
    }                                                                           \
    /* h^T frags */                                                             \
    bf16x8 hb[4];                                                               \
    _Pragma("unroll")                                                           \
    for (int kt = 0; kt < 4; ++kt)                                              \
      hb[kt] = *(const bf16x8*)&lds_h[l15 * LDH_STRIDE + kt * 32 + lk * 8];     \
    const float av = lds_att[t_ * 16 + l15];                                    \
    /* phase1: z,r (split-k depth 2) */                                         \
    f32x4 zA = accP[CUR][0], rA = accP[CUR][1], zB, rB;                         \
    zB[0]=0.f; zB[1]=0.f; zB[2]=0.f; zB[3]=0.f; rB = zB;                        \
    zA = __builtin_amdgcn_mfma_f32_16x16x32_bf16(wzH[0], hb[0], zA, 0, 0, 0);   \
    rA = __builtin_amdgcn_mfma_f32_16x16x32_bf16(wrH[0], hb[0], rA, 0, 0, 0);   \
    zB = __builtin_amdgcn_mfma_f32_16x16x32_bf16(wzH[2], hb[2], zB, 0, 0, 0);   \
    rB = __builtin_amdgcn_mfma_f32_16x16x32_bf16(wrH[2], hb[2], rB, 0, 0, 0);   \
    zA = __builtin_amdgcn_mfma_f32_16x16x32_bf16(wzH[1], hb[1], zA, 0, 0, 0);   \
    rA = __builtin_amdgcn_mfma_f32_16x16x32_bf16(wrH[1], hb[1], rA, 0, 0, 0);   \
    zB = __builtin_amdgcn_mfma_f32_16x16x32_bf16(wzH[3], hb[3], zB, 0, 0, 0);   \
    rB = __builtin_amdgcn_mfma_f32_16x16x32_bf16(wrH[3], hb[3], rB, 0, 0, 0);   \
    /* gates in registers; rh -> LDS (one b64) */                               \
    float zp[4]; bf16x4 rhv;                                                    \
    _Pragma("unroll")                                                           \
    for (int q = 0; q < 4; ++q) {                                               \
      zp[q] = av * fast_sigmoid(zA[q] + zB[q]);                                 \
      float rr = fast_sigmoid(rA[q] + rB[q]);                                   \
      rhv[q] = (__bf16)(rr * hreg[q]);                                          \
    }                                                                           \
    *(bf16x4*)&lds_rh[l15 * LDH_STRIDE + myhid] = rhv;                          \
    barrier_lds();                                                              \
    /* phase2: h~ (split-k depth 2) */                                          \
    bf16x8 rb[4];                                                               \
    _Pragma("unroll")                                                           \
    for (int kt = 0; kt < 4; ++kt)                                              \
      rb[kt] = *(const bf16x8*)&lds_rh[l15 * LDH_STRIDE + kt * 32 + lk * 8];    \
    f32x4 hA = accP[CUR][2], hB;                                                \
    hB[0]=0.f; hB[1]=0.f; hB[2]=0.f; hB[3]=0.f;                                 \
    hA = __builtin_amdgcn_mfma_f32_16x16x32_bf16(whH[0], rb[0], hA, 0, 0, 0);   \
    hB = __builtin_amdgcn_mfma_f32_16x16x32_bf16(whH[2], rb[2], hB, 0, 0, 0);   \
    hA = __builtin_amdgcn_mfma_f32_16x16x32_bf16(whH[1], rb[1], hA, 0, 0, 0);   \
    hB = __builtin_amdgcn_mfma_f32_16x16x32_bf16(whH[3], rb[3], hB, 0, 0, 0);   \
    /* x-part MFMAs for t+1 (operands prefetched 2 steps ago -> no stall);      \
       fills MFMA pipe while update waits on phase2 latency */                  \
    if (t_ + 1 < T_N) {                                                         \
      _Pragma("unroll")                                                         \
      for (int g = 0; g < 3; ++g) accP[NXT][g] = bias4[g];                      \
      _Pragma("unroll")                                                         \
      for (int kt = 0; kt < 4; ++kt) {                                          \
        accP[NXT][0] = __builtin_amdgcn_mfma_f32_16x16x32_bf16(wzX[kt], XC[kt], accP[NXT][0], 0, 0, 0); \
        accP[NXT][1] = __builtin_amdgcn_mfma_f32_16x16x32_bf16(wrX[kt], XC[kt], accP[NXT][1], 0, 0, 0); \
        accP[NXT][2] = __builtin_amdgcn_mfma_f32_16x16x32_bf16(whX[kt], XC[kt], accP[NXT][2], 0, 0, 0); \
      }                                                                         \
    }                                                                           \
    /* update h */                                                              \
    bf16x4 hbv;                                                                 \
    _Pragma("unroll")                                                           \
    for (int q = 0; q < 4; ++q) {                                               \
      float ht = fast_tanh(hA[q] + hB[q]);                                      \
      float hn = __builtin_fmaf(zp[q], ht - hreg[q], hreg[q]);                  \
      hreg[q] = hn;                                                             \
      hbv[q] = (__bf16)hn;                                                      \
    }                                                                           \
    *(bf16x4*)&lds_h[l15 * LDH_STRIDE + myhid] = hbv;                           \
    barrier_lds();                                                              \
  }

  for (int tt = 0; tt < T_N; tt += 2) {
    STEP_BODY(tt,     0, 1, xA, xB)
    STEP_BODY(tt + 1, 1, 0, xB, xA)
  }
#undef STEP_BODY

  // ---- epilogue ----
  float4 o;
  o.x = hreg[0]; o.y = hreg[1]; o.z = hreg[2]; o.w = hreg[3];
  *(float4*)&out[(size_t)(r0 + l15) * H_DIM + myhid] = o;
}

// ---------------------------------------------------------------------------
// Fallback: proven single-kernel version (round 2, 410 us).
// ---------------------------------------------------------------------------
__global__ __launch_bounds__(256, 1)
void augru_kernel(const float* __restrict__ inputs,
                  const float* __restrict__ attn,
                  const float* __restrict__ Wz, const float* __restrict__ bz,
                  const float* __restrict__ Wr, const float* __restrict__ br,
                  const float* __restrict__ Wh, const float* __restrict__ bh,
                  float* __restrict__ out) {
  __shared__ __align__(16) short lds_a[16 * LDA_STRIDE];
  __shared__ float lds_att[16 * LATT_STRIDE];

  const int tid = threadIdx.x;
  const int w   = tid >> 6;
  const int l   = tid & 63;
  const int l15 = l & 15;
  const int lk  = l >> 4;
  const int r0  = blockIdx.x * 16;

  for (int idx = tid; idx < 16 * T_N; idx += 256) {
    int row = idx / T_N, t = idx - row * T_N;
    lds_att[row * LATT_STRIDE + t] = attn[(size_t)(r0 + row) * T_N + t];
  }
  for (int idx = tid; idx < 16 * H_DIM; idx += 256) {
    int row = idx >> 7, c = idx & 127;
    lds_a[row * LDA_STRIDE + c] = 0;
  }

  bf16x8 w1[32];
  float  bias1[4];
  #pragma unroll
  for (int ct = 0; ct < 4; ++ct) {
    int n = w * 32 + (ct & 1) * 16 + l15;
    const float* Wp; float bv;
    if (ct < 2) { Wp = Wz + (size_t)n * 256; bv = bz[n]; }
    else        { Wp = Wr + (size_t)n * 256; bv = br[n]; }
    bias1[ct] = bv;
    #pragma unroll
    for (int kt = 0; kt < 8; ++kt) {
      const float* p = Wp + kt * 32 + lk * 8;
      w1[ct * 8 + kt] = pack8(*(const float4*)p, *(const float4*)(p + 4));
    }
  }
  bf16x8 w2[16];
  float  bias2[2];
  #pragma unroll
  for (int ct = 0; ct < 2; ++ct) {
    int n = w * 32 + ct * 16 + l15;
    bias2[ct] = bh[n];
    const float* Wp = Wh + (size_t)n * 256;
    #pragma unroll
    for (int kt = 0; kt < 8; ++kt) {
      const float* p = Wp + kt * 32 + lk * 8;
      w2[ct * 8 + kt] = pack8(*(const float4*)p, *(const float4*)(p + 4));
    }
  }

  float hreg[2][4];
  #pragma unroll
  for (int ct = 0; ct < 2; ++ct)
    #pragma unroll
    for (int q = 0; q < 4; ++q) hreg[ct][q] = 0.0f;

  const float* xbase = inputs + (size_t)(r0 + l15) * (T_N * I_DIM);
  bf16x8 xfrag[4];
  #pragma unroll
  for (int kt = 0; kt < 4; ++kt) {
    const float* p = xbase + kt * 32 + lk * 8;
    xfrag[kt] = pack8(*(const float4*)p, *(const float4*)(p + 4));
  }

  __syncthreads();

  float4 xr0[4], xr1[4];
  for (int t = 0; t < T_N; ++t) {
    if (t + 1 < T_N) {
      #pragma unroll
      for (int kt = 0; kt < 4; ++kt) {
        const float* p = xbase + (size_t)(t + 1) * I_DIM + kt * 32 + lk * 8;
        xr0[kt] = *(const float4*)p;
        xr1[kt] = *(const float4*)(p + 4);
      }
    }
    bf16x8 hfrag[4];
    #pragma unroll
    for (int kt = 0; kt < 4; ++kt)
      hfrag[kt] = *(const bf16x8*)&lds_a[l15 * LDA_STRIDE + kt * 32 + lk * 8];
    float av[4];
    #pragma unroll
    for (int q = 0; q < 4; ++q) av[q] = lds_att[(lk * 4 + q) * LATT_STRIDE + t];

    f32x4 acc[4];
    #pragma unroll
    for (int ct = 0; ct < 4; ++ct) {
      f32x4 a; a[0] = bias1[ct]; a[1] = bias1[ct]; a[2] = bias1[ct]; a[3] = bias1[ct];
      acc[ct] = a;
    }
    #pragma unroll
    for (int kt = 0; kt < 4; ++kt)
      #pragma unroll
      for (int ct = 0; ct < 4; ++ct)
        acc[ct] = __builtin_amdgcn_mfma_f32_16x16x32_bf16(xfrag[kt], w1[ct * 8 + kt], acc[ct], 0, 0, 0);

    f32x4 acc2[2];
    #pragma unroll
    for (int ct = 0; ct < 2; ++ct) {
      f32x4 a; a[0] = bias2[ct]; a[1] = bias2[ct]; a[2] = bias2[ct]; a[3] = bias2[ct];
      acc2[ct] = a;
    }
    #pragma unroll
    for (int kt = 0; kt < 4; ++kt)
      #pragma unroll
      for (int ct = 0; ct < 2; ++ct)
        acc2[ct] = __builtin_amdgcn_mfma_f32_16x16x32_bf16(xfrag[kt], w2[ct * 8 + kt], acc2[ct], 0, 0, 0);

    #pragma unroll
    for (int kt = 0; kt < 4; ++kt)
      #pragma unroll
      for (int ct = 0; ct < 4; ++ct)
        acc[ct] = __builtin_amdgcn_mfma_f32_16x16x32_bf16(hfrag[kt], w1[ct * 8 + 4 + kt], acc[ct], 0, 0, 0);

    float zp[2][4];
    #pragma unroll
    for (int ct = 0; ct < 2; ++ct) {
      int col = w * 32 + ct * 16 + l15;
      #pragma unroll
      for (int q = 0; q < 4; ++q) {
        int row = lk * 4 + q;
        zp[ct][q] = av[q] * fast_sigmoid(acc[ct][q]);
        float rr = fast_sigmoid(acc[2 + ct][q]);
        __bf16 rhb = (__bf16)(rr * hreg[ct][q]);
        lds_a[row * LDA_STRIDE + 128 + col] = __builtin_bit_cast(short, rhb);
      }
    }
    barrier_lds();

    bf16x8 rfrag[4];
    #pragma unroll
    for (int kt = 0; kt < 4; ++kt)
      rfrag[kt] = *(const bf16x8*)&lds_a[l15 * LDA_STRIDE + 128 + kt * 32 + lk * 8];
    #pragma unroll
    for (int kt = 0; kt < 4; ++kt)
      #pragma unroll
      for (int ct = 0; ct < 2; ++ct)
        acc2[ct] = __builtin_amdgcn_mfma_f32_16x16x32_bf16(rfrag[kt], w2[ct * 8 + 4 + kt], acc2[ct], 0, 0, 0);

    if (t + 1 < T_N) {
      #pragma unroll
      for (int kt = 0; kt < 4; ++kt)
        xfrag[kt] = pack8(xr0[kt], xr1[kt]);
    }

    #pragma unroll
    for (int ct = 0; ct < 2; ++ct) {
      int col = w * 32 + ct * 16 + l15;
      #pragma unroll
      for (int q = 0; q < 4; ++q) {
        int row = lk * 4 + q;
        float ht = fast_tanh(acc2[ct][q]);
        float ho = hreg[ct][q];
        float hn = __builtin_fmaf(zp[ct][q], ht - ho, ho);
        hreg[ct][q] = hn;
        __bf16 hb = (__bf16)hn;
        lds_a[row * LDA_STRIDE + col] = __builtin_bit_cast(short, hb);
      }
    }
    barrier_lds();
  }

  #pragma unroll
  for (int ct = 0; ct < 2; ++ct) {
    int col = w * 32 + ct * 16 + l15;
    #pragma unroll
    for (int q = 0; q < 4; ++q) {
      int row = lk * 4 + q;
      out[(size_t)(r0 + row) * H_DIM + col] = hreg[ct][q];
    }
  }
}

extern "C" void kernel_launch(void* const* d_in, const int* in_sizes, int n_in,
                              void* d_out, int out_size, void* d_ws, size_t ws_size,
                              hipStream_t stream) {
  (void)in_sizes; (void)n_in; (void)out_size;
  const float* inputs = (const float*)d_in[0];
  const float* attn   = (const float*)d_in[1];
  const float* Wz     = (const float*)d_in[2];
  const float* bz     = (const float*)d_in[3];
  const float* Wr     = (const float*)d_in[4];
  const float* br     = (const float*)d_in[5];
  const float* Wh     = (const float*)d_in[6];
  const float* bh     = (const float*)d_in[7];
  float* out = (float*)d_out;

  if (ws_size >= XCAST_BYTES) {
    __bf16* xb = (__bf16*)d_ws;
    const size_t nelem = (size_t)1024 * T_N * I_DIM;          // 26,214,400
    xcast_kernel<<<(int)(nelem / (256 * 8)), 256, 0, stream>>>(inputs, xb);
    augru_fused_kernel<<<NBLK, 512, 0, stream>>>(xb, attn, Wz, bz, Wr, br, Wh, bh, out);
  } else {
    augru_kernel<<<NBLK, 256, 0, stream>>>(inputs, attn, Wz, bz, Wr, br, Wh, bh, out);
  }
}

// Round 9
// 276.050 us; speedup vs baseline: 1.2297x; 1.0928x over previous
//
#include <hip/hip_runtime.h>

// AUGRU, round 9: two-pass, transposed rec + XOR-swizzled LDS + coalesced
// preact layout on both producer and consumer sides.
//  Pass 1 (xproj): D[hid][batch] = Wx(A) x x^T(B) + bias -> bf16 preacts,
//     layout [t][bblk][gate(3)][hidgrp(32)][batch(16) x bf16x4] (coalesced).
//  Pass 2 (rec): 64 blocks x 8 waves. lds_h/lds_rh: [16 batch][128 hid] bf16,
//     NO pad, XOR swizzle byte ^= ((row&7)<<4) -> near-floor bank behavior.
//     z'/h in registers; rh/h exchanged via one b64 write per thread.
// Fallback: proven single-kernel (R2) if ws too small.

#define T_N   200
#define I_DIM 128
#define H_DIM 128
#define NBLK  64

typedef float  f32x4  __attribute__((ext_vector_type(4)));
typedef __bf16 bf16x4 __attribute__((ext_vector_type(4)));
typedef __bf16 bf16x8 __attribute__((ext_vector_type(8)));

// preact layout: g*4096 + (hid>>2)*128 + b*8 + (hid&3)*2 ; per (t,bblk) 12288 B
#define GATE_BYTES 4096
#define PB_BYTES   (3 * GATE_BYTES)
#define PRE_BYTES  ((size_t)T_N * NBLK * PB_BYTES)   // 157,286,400

// fallback LDS
#define LDA_STRIDE 264
#define LATT_STRIDE 201

__device__ __forceinline__ float fast_sigmoid(float x) {
  float e = __builtin_amdgcn_exp2f(-1.4426950408889634f * x);
  return __builtin_amdgcn_rcpf(1.0f + e);
}
__device__ __forceinline__ float fast_tanh(float x) {
  float e = __builtin_amdgcn_exp2f(2.8853900817779268f * x);
  return 1.0f - 2.0f * __builtin_amdgcn_rcpf(1.0f + e);
}
__device__ __forceinline__ void barrier_lds() {
  asm volatile("s_waitcnt lgkmcnt(0)\n\ts_barrier" ::: "memory");
}
__device__ __forceinline__ bf16x8 pack8(float4 a, float4 b) {
  bf16x8 t;
  t[0] = (__bf16)a.x; t[1] = (__bf16)a.y; t[2] = (__bf16)a.z; t[3] = (__bf16)a.w;
  t[4] = (__bf16)b.x; t[5] = (__bf16)b.y; t[6] = (__bf16)b.z; t[7] = (__bf16)b.w;
  return t;
}
// XOR-swizzled byte offset within a [16 row][256 B] LDS tile
__device__ __forceinline__ int swz(int row, int bytecol) {
  return row * 256 + (bytecol ^ ((row & 7) << 4));
}

// ---------------------------------------------------------------------------
// Pass 1: x-projections (transposed). grid = 64 bblk * 20 tchunks, 256 thr.
// ---------------------------------------------------------------------------
#define TCHUNK 10
__global__ __launch_bounds__(256, 2)
void xproj_kernel(const float* __restrict__ inputs,
                  const float* __restrict__ Wz, const float* __restrict__ bz,
                  const float* __restrict__ Wr, const float* __restrict__ br,
                  const float* __restrict__ Wh, const float* __restrict__ bh,
                  char* __restrict__ pre) {
  const int tid  = threadIdx.x;
  const int w    = tid >> 6;
  const int l    = tid & 63;
  const int l15  = l & 15;
  const int lk   = l >> 4;
  const int bblk = blockIdx.x & (NBLK - 1);
  const int t0   = (blockIdx.x >> 6) * TCHUNK;
  const int r0   = bblk * 16;

  // A-frags: W x-part (k=0..127). slot s: gate g=s>>1, hid0 = w*32+(s&1)*16.
  bf16x8 wb[24];
  f32x4  bias4[6];
  #pragma unroll
  for (int s = 0; s < 6; ++s) {
    int hid0 = w * 32 + (s & 1) * 16;
    const float* Wp; const float* bp;
    if (s < 2)      { Wp = Wz; bp = bz; }
    else if (s < 4) { Wp = Wr; bp = br; }
    else            { Wp = Wh; bp = bh; }
    float4 bv = *(const float4*)&bp[hid0 + lk * 4];
    bias4[s][0] = bv.x; bias4[s][1] = bv.y; bias4[s][2] = bv.z; bias4[s][3] = bv.w;
    const float* Wrow = Wp + (size_t)(hid0 + l15) * 256;
    #pragma unroll
    for (int kt = 0; kt < 4; ++kt) {
      const float* p = Wrow + kt * 32 + lk * 8;
      wb[s * 4 + kt] = pack8(*(const float4*)p, *(const float4*)(p + 4));
    }
  }

  const float* xbase = inputs + (size_t)(r0 + l15) * (T_N * I_DIM);

  #pragma unroll 2
  for (int ti = 0; ti < TCHUNK; ++ti) {
    const int t = t0 + ti;
    bf16x8 xf[4];
    #pragma unroll
    for (int kt = 0; kt < 4; ++kt) {
      const float* p = xbase + (size_t)t * I_DIM + kt * 32 + lk * 8;
      xf[kt] = pack8(*(const float4*)p, *(const float4*)(p + 4));
    }
    f32x4 acc[6];
    #pragma unroll
    for (int s = 0; s < 6; ++s) acc[s] = bias4[s];
    #pragma unroll
    for (int kt = 0; kt < 4; ++kt)
      #pragma unroll
      for (int s = 0; s < 6; ++s)
        acc[s] = __builtin_amdgcn_mfma_f32_16x16x32_bf16(wb[s * 4 + kt], xf[kt], acc[s], 0, 0, 0);

    // store coalesced: hidgrp = w*8 + (s&1)*4 + lk ; addr = g*4096+hidgrp*128+l15*8
    char* base = pre + ((size_t)t * NBLK + bblk) * PB_BYTES;
    #pragma unroll
    for (int s = 0; s < 6; ++s) {
      int g      = s >> 1;
      int hidgrp = w * 8 + (s & 1) * 4 + lk;
      bf16x4 v;
      v[0] = (__bf16)acc[s][0]; v[1] = (__bf16)acc[s][1];
      v[2] = (__bf16)acc[s][2]; v[3] = (__bf16)acc[s][3];
      *(bf16x4*)(base + g * GATE_BYTES + hidgrp * 128 + l15 * 8) = v;
    }
  }
}

// ---------------------------------------------------------------------------
// Pass 2: recurrence (transposed, swizzled LDS). 64 blocks, 512 threads.
// ---------------------------------------------------------------------------
__global__ __launch_bounds__(512, 1)
void augru_rec_kernel(const char* __restrict__ pre,
                      const float* __restrict__ attn,
                      const float* __restrict__ Wz,
                      const float* __restrict__ Wr,
                      const float* __restrict__ Wh,
                      float* __restrict__ out) {
  __shared__ __align__(16) short lds_h [16 * 128];  // hT  [batch][hid], swizzled
  __shared__ __align__(16) short lds_rh[16 * 128];  // rhT [batch][hid], swizzled
  __shared__ float lds_att[T_N * 16];               // [t][batch]

  const int tid   = threadIdx.x;
  const int w     = tid >> 6;
  const int l     = tid & 63;
  const int l15   = l & 15;          // batch lane
  const int lk    = l >> 4;
  const int r0    = blockIdx.x * 16;
  const int myhid = w * 16 + lk * 4; // thread's 4 contiguous hidden rows

  // ---- prologue ----
  for (int idx = tid; idx < T_N * 16; idx += 512) {
    int t = idx >> 4, b = idx & 15;
    lds_att[idx] = attn[(size_t)(r0 + b) * T_N + t];
  }
  for (int idx = tid; idx < 16 * 128; idx += 512) lds_h[idx] = 0;

  // ---- A-frags: recurrent weights (k=128..255), rows = hidden w*16+l15 ----
  bf16x8 wzH[4], wrH[4], whH[4];
  {
    const float* pz = Wz + (size_t)(w * 16 + l15) * 256 + 128;
    const float* pr = Wr + (size_t)(w * 16 + l15) * 256 + 128;
    const float* ph = Wh + (size_t)(w * 16 + l15) * 256 + 128;
    #pragma unroll
    for (int kt = 0; kt < 4; ++kt) {
      const float* a = pz + kt * 32 + lk * 8;
      wzH[kt] = pack8(*(const float4*)a, *(const float4*)(a + 4));
      const float* b = pr + kt * 32 + lk * 8;
      wrH[kt] = pack8(*(const float4*)b, *(const float4*)(b + 4));
      const float* c = ph + kt * 32 + lk * 8;
      whH[kt] = pack8(*(const float4*)c, *(const float4*)(c + 4));
    }
  }

  float hreg[4];
  #pragma unroll
  for (int q = 0; q < 4; ++q) hreg[q] = 0.0f;

  // ---- preact ring (depth 2), coalesced: 8B at (w*4+lk)*128 + l15*8 ----
  const char* pb = pre + (size_t)blockIdx.x * PB_BYTES + (w * 4 + lk) * 128 + l15 * 8;
  const size_t tstride = (size_t)NBLK * PB_BYTES;
  bf16x4 pf[2][3];
  #pragma unroll
  for (int d = 0; d < 2; ++d)
    #pragma unroll
    for (int g = 0; g < 3; ++g)
      pf[d][g] = *(const bf16x4*)(pb + d * tstride + g * GATE_BYTES);

  // swizzled LDS byte offsets (constant per thread, except kt)
  const int wr_off = swz(l15, 32 * w + 8 * lk);   // b64 write: myhid*2 bytes

  __syncthreads();

  #pragma unroll 2
  for (int t = 0; t < T_N; ++t) {
    // consume preact t
    float pzv[4], prv[4], phv[4];
    #pragma unroll
    for (int q = 0; q < 4; ++q) {
      pzv[q] = (float)pf[t & 1][0][q];
      prv[q] = (float)pf[t & 1][1][q];
      phv[q] = (float)pf[t & 1][2][q];
    }
    // prefetch t+2
    if (t + 2 < T_N) {
      const char* b = pb + (size_t)(t + 2) * tstride;
      #pragma unroll
      for (int g = 0; g < 3; ++g)
        pf[t & 1][g] = *(const bf16x4*)(b + g * GATE_BYTES);
    }

    // B-frags: h^T (swizzled reads, consumed in load order)
    bf16x8 hb[4];
    #pragma unroll
    for (int kt = 0; kt < 4; ++kt)
      hb[kt] = *(const bf16x8*)((const char*)lds_h + swz(l15, kt * 64 + lk * 16));
    const float av = lds_att[t * 16 + l15];

    // phase1: chains A={kt0,kt2}, B={kt1,kt3}; consume kt in order
    f32x4 zA, zB, rA, rB;
    { f32x4 a; a[0]=pzv[0]; a[1]=pzv[1]; a[2]=pzv[2]; a[3]=pzv[3]; zA = a; }
    { f32x4 a; a[0]=prv[0]; a[1]=prv[1]; a[2]=prv[2]; a[3]=prv[3]; rA = a; }
    { f32x4 z; z[0]=0.f; z[1]=0.f; z[2]=0.f; z[3]=0.f; zB = z; rB = z; }
    zA = __builtin_amdgcn_mfma_f32_16x16x32_bf16(wzH[0], hb[0], zA, 0, 0, 0);
    rA = __builtin_amdgcn_mfma_f32_16x16x32_bf16(wrH[0], hb[0], rA, 0, 0, 0);
    zB = __builtin_amdgcn_mfma_f32_16x16x32_bf16(wzH[1], hb[1], zB, 0, 0, 0);
    rB = __builtin_amdgcn_mfma_f32_16x16x32_bf16(wrH[1], hb[1], rB, 0, 0, 0);
    zA = __builtin_amdgcn_mfma_f32_16x16x32_bf16(wzH[2], hb[2], zA, 0, 0, 0);
    rA = __builtin_amdgcn_mfma_f32_16x16x32_bf16(wrH[2], hb[2], rA, 0, 0, 0);
    zB = __builtin_amdgcn_mfma_f32_16x16x32_bf16(wzH[3], hb[3], zB, 0, 0, 0);
    rB = __builtin_amdgcn_mfma_f32_16x16x32_bf16(wrH[3], hb[3], rB, 0, 0, 0);

    // r first (critical: feeds rh write), then z' (off-critical)
    bf16x4 rhv;
    #pragma unroll
    for (int q = 0; q < 4; ++q) {
      float rr = fast_sigmoid(rA[q] + rB[q]);
      rhv[q] = (__bf16)(rr * hreg[q]);
    }
    *(bf16x4*)((char*)lds_rh + wr_off) = rhv;
    float zp[4];
    #pragma unroll
    for (int q = 0; q < 4; ++q)
      zp[q] = av * fast_sigmoid(zA[q] + zB[q]);
    barrier_lds();  // B1: rh visible; preact prefetch stays in flight

    // phase2: h~ (swizzled rb reads, consume in order)
    bf16x8 rb[4];
    #pragma unroll
    for (int kt = 0; kt < 4; ++kt)
      rb[kt] = *(const bf16x8*)((const char*)lds_rh + swz(l15, kt * 64 + lk * 16));
    f32x4 hA, hB;
    { f32x4 a; a[0]=phv[0]; a[1]=phv[1]; a[2]=phv[2]; a[3]=phv[3]; hA = a; }
    { f32x4 z; z[0]=0.f; z[1]=0.f; z[2]=0.f; z[3]=0.f; hB = z; }
    hA = __builtin_amdgcn_mfma_f32_16x16x32_bf16(whH[0], rb[0], hA, 0, 0, 0);
    hB = __builtin_amdgcn_mfma_f32_16x16x32_bf16(whH[1], rb[1], hB, 0, 0, 0);
    hA = __builtin_amdgcn_mfma_f32_16x16x32_bf16(whH[2], rb[2], hA, 0, 0, 0);
    hB = __builtin_amdgcn_mfma_f32_16x16x32_bf16(whH[3], rb[3], hB, 0, 0, 0);

    // update h
    bf16x4 hbv;
    #pragma unroll
    for (int q = 0; q < 4; ++q) {
      float ht = fast_tanh(hA[q] + hB[q]);
      float hn = __builtin_fmaf(zp[q], ht - hreg[q], hreg[q]);
      hreg[q] = hn;
      hbv[q] = (__bf16)hn;
    }
    *(bf16x4*)((char*)lds_h + wr_off) = hbv;
    barrier_lds();  // B2: h visible for next phase1
  }

  // ---- epilogue: contiguous float4 store ----
  float4 o;
  o.x = hreg[0]; o.y = hreg[1]; o.z = hreg[2]; o.w = hreg[3];
  *(float4*)&out[(size_t)(r0 + l15) * H_DIM + myhid] = o;
}

// ---------------------------------------------------------------------------
// Fallback: proven single-kernel version (round 2, 410 us).
// ---------------------------------------------------------------------------
__global__ __launch_bounds__(256, 1)
void augru_kernel(const float* __restrict__ inputs,
                  const float* __restrict__ attn,
                  const float* __restrict__ Wz, const float* __restrict__ bz,
                  const float* __restrict__ Wr, const float* __restrict__ br,
                  const float* __restrict__ Wh, const float* __restrict__ bh,
                  float* __restrict__ out) {
  __shared__ __align__(16) short lds_a[16 * LDA_STRIDE];
  __shared__ float lds_att[16 * LATT_STRIDE];

  const int tid = threadIdx.x;
  const int w   = tid >> 6;
  const int l   = tid & 63;
  const int l15 = l & 15;
  const int lk  = l >> 4;
  const int r0  = blockIdx.x * 16;

  for (int idx = tid; idx < 16 * T_N; idx += 256) {
    int row = idx / T_N, t = idx - row * T_N;
    lds_att[row * LATT_STRIDE + t] = attn[(size_t)(r0 + row) * T_N + t];
  }
  for (int idx = tid; idx < 16 * H_DIM; idx += 256) {
    int row = idx >> 7, c = idx & 127;
    lds_a[row * LDA_STRIDE + c] = 0;
  }

  bf16x8 w1[32];
  float  bias1[4];
  #pragma unroll
  for (int ct = 0; ct < 4; ++ct) {
    int n = w * 32 + (ct & 1) * 16 + l15;
    const float* Wp; float bv;
    if (ct < 2) { Wp = Wz + (size_t)n * 256; bv = bz[n]; }
    else        { Wp = Wr + (size_t)n * 256; bv = br[n]; }
    bias1[ct] = bv;
    #pragma unroll
    for (int kt = 0; kt < 8; ++kt) {
      const float* p = Wp + kt * 32 + lk * 8;
      w1[ct * 8 + kt] = pack8(*(const float4*)p, *(const float4*)(p + 4));
    }
  }
  bf16x8 w2[16];
  float  bias2[2];
  #pragma unroll
  for (int ct = 0; ct < 2; ++ct) {
    int n = w * 32 + ct * 16 + l15;
    bias2[ct] = bh[n];
    const float* Wp = Wh + (size_t)n * 256;
    #pragma unroll
    for (int kt = 0; kt < 8; ++kt) {
      const float* p = Wp + kt * 32 + lk * 8;
      w2[ct * 8 + kt] = pack8(*(const float4*)p, *(const float4*)(p + 4));
    }
  }

  float hreg[2][4];
  #pragma unroll
  for (int ct = 0; ct < 2; ++ct)
    #pragma unroll
    for (int q = 0; q < 4; ++q) hreg[ct][q] = 0.0f;

  const float* xbase = inputs + (size_t)(r0 + l15) * (T_N * I_DIM);
  bf16x8 xfrag[4];
  #pragma unroll
  for (int kt = 0; kt < 4; ++kt) {
    const float* p = xbase + kt * 32 + lk * 8;
    xfrag[kt] = pack8(*(const float4*)p, *(const float4*)(p + 4));
  }

  __syncthreads();

  float4 xr0[4], xr1[4];
  for (int t = 0; t < T_N; ++t) {
    if (t + 1 < T_N) {
      #pragma unroll
      for (int kt = 0; kt < 4; ++kt) {
        const float* p = xbase + (size_t)(t + 1) * I_DIM + kt * 32 + lk * 8;
        xr0[kt] = *(const float4*)p;
        xr1[kt] = *(const float4*)(p + 4);
      }
    }
    bf16x8 hfrag[4];
    #pragma unroll
    for (int kt = 0; kt < 4; ++kt)
      hfrag[kt] = *(const bf16x8*)&lds_a[l15 * LDA_STRIDE + kt * 32 + lk * 8];
    float av[4];
    #pragma unroll
    for (int q = 0; q < 4; ++q) av[q] = lds_att[(lk * 4 + q) * LATT_STRIDE + t];

    f32x4 acc[4];
    #pragma unroll
    for (int ct = 0; ct < 4; ++ct) {
      f32x4 a; a[0] = bias1[ct]; a[1] = bias1[ct]; a[2] = bias1[ct]; a[3] = bias1[ct];
      acc[ct] = a;
    }
    #pragma unroll
    for (int kt = 0; kt < 4; ++kt)
      #pragma unroll
      for (int ct = 0; ct < 4; ++ct)
        acc[ct] = __builtin_amdgcn_mfma_f32_16x16x32_bf16(xfrag[kt], w1[ct * 8 + kt], acc[ct], 0, 0, 0);

    f32x4 acc2[2];
    #pragma unroll
    for (int ct = 0; ct < 2; ++ct) {
      f32x4 a; a[0] = bias2[ct]; a[1] = bias2[ct]; a[2] = bias2[ct]; a[3] = bias2[ct];
      acc2[ct] = a;
    }
    #pragma unroll
    for (int kt = 0; kt < 4; ++kt)
      #pragma unroll
      for (int ct = 0; ct < 2; ++ct)
        acc2[ct] = __builtin_amdgcn_mfma_f32_16x16x32_bf16(xfrag[kt], w2[ct * 8 + kt], acc2[ct], 0, 0, 0);

    #pragma unroll
    for (int kt = 0; kt < 4; ++kt)
      #pragma unroll
      for (int ct = 0; ct < 4; ++ct)
        acc[ct] = __builtin_amdgcn_mfma_f32_16x16x32_bf16(hfrag[kt], w1[ct * 8 + 4 + kt], acc[ct], 0, 0, 0);

    float zp[2][4];
    #pragma unroll
    for (int ct = 0; ct < 2; ++ct) {
      int col = w * 32 + ct * 16 + l15;
      #pragma unroll
      for (int q = 0; q < 4; ++q) {
        int row = lk * 4 + q;
        zp[ct][q] = av[q] * fast_sigmoid(acc[ct][q]);
        float rr = fast_sigmoid(acc[2 + ct][q]);
        __bf16 rhb = (__bf16)(rr * hreg[ct][q]);
        lds_a[row * LDA_STRIDE + 128 + col] = __builtin_bit_cast(short, rhb);
      }
    }
    barrier_lds();

    bf16x8 rfrag[4];
    #pragma unroll
    for (int kt = 0; kt < 4; ++kt)
      rfrag[kt] = *(const bf16x8*)&lds_a[l15 * LDA_STRIDE + 128 + kt * 32 + lk * 8];
    #pragma unroll
    for (int kt = 0; kt < 4; ++kt)
      #pragma unroll
      for (int ct = 0; ct < 2; ++ct)
        acc2[ct] = __builtin_amdgcn_mfma_f32_16x16x32_bf16(rfrag[kt], w2[ct * 8 + 4 + kt], acc2[ct], 0, 0, 0);

    if (t + 1 < T_N) {
      #pragma unroll
      for (int kt = 0; kt < 4; ++kt)
        xfrag[kt] = pack8(xr0[kt], xr1[kt]);
    }

    #pragma unroll
    for (int ct = 0; ct < 2; ++ct) {
      int col = w * 32 + ct * 16 + l15;
      #pragma unroll
      for (int q = 0; q < 4; ++q) {
        int row = lk * 4 + q;
        float ht = fast_tanh(acc2[ct][q]);
        float ho = hreg[ct][q];
        float hn = __builtin_fmaf(zp[ct][q], ht - ho, ho);
        hreg[ct][q] = hn;
        __bf16 hb = (__bf16)hn;
        lds_a[row * LDA_STRIDE + col] = __builtin_bit_cast(short, hb);
      }
    }
    barrier_lds();
  }

  #pragma unroll
  for (int ct = 0; ct < 2; ++ct) {
    int col = w * 32 + ct * 16 + l15;
    #pragma unroll
    for (int q = 0; q < 4; ++q) {
      int row = lk * 4 + q;
      out[(size_t)(r0 + row) * H_DIM + col] = hreg[ct][q];
    }
  }
}

extern "C" void kernel_launch(void* const* d_in, const int* in_sizes, int n_in,
                              void* d_out, int out_size, void* d_ws, size_t ws_size,
                              hipStream_t stream) {
  (void)in_sizes; (void)n_in; (void)out_size;
  const float* inputs = (const float*)d_in[0];
  const float* attn   = (const float*)d_in[1];
  const float* Wz     = (const float*)d_in[2];
  const float* bz     = (const float*)d_in[3];
  const float* Wr     = (const float*)d_in[4];
  const float* br     = (const float*)d_in[5];
  const float* Wh     = (const float*)d_in[6];
  const float* bh     = (const float*)d_in[7];
  float* out = (float*)d_out;

  if (ws_size >= PRE_BYTES) {
    char* pre = (char*)d_ws;
    xproj_kernel<<<NBLK * (T_N / TCHUNK), 256, 0, stream>>>(inputs, Wz, bz, Wr, br, Wh, bh, pre);
    augru_rec_kernel<<<NBLK, 512, 0, stream>>>(pre, attn, Wz, Wr, Wh, out);
  } else {
    augru_kernel<<<NBLK, 256, 0, stream>>>(inputs, attn, Wz, bz, Wr, br, Wh, bh, out);
  }
}